// Round 5
// baseline (425.111 us; speedup 1.0000x reference)
//
#include <hip/hip_runtime.h>
#include <cstdint>
#include <cstddef>

// Problem constants
#define T_TOK 8192
#define K_CODE 8192
#define C_DIM 512
#define BETA 0.25f
#define DECAY 0.99f
#define ONE_MINUS_DECAY 0.01f
#define EPS_F 1e-5f
#define K_EPS 0.08192f
// Coarse-dist worst-case error bound: 2*||z||*||e||*2^-10 <= 0.025; margin = 2E + cushion
#define MARGIN 0.0625f

// d_out layout (floats, concatenated in reference return order)
#define ZQ_OFF   ((size_t)0)          // z_q_st      [8,1024,512] = 4194304
#define IDX_OFF  ((size_t)4194304)    // indices     [8,1024]     = 8192
#define LOSS_OFF ((size_t)4202496)    // vq_loss     scalar       = 1
#define NCB_OFF  ((size_t)4202497)    // new_codebook[8192,512]   = 4194304
#define NCS_OFF  ((size_t)8396801)    // new_cluster [8192]       = 8192
#define NEA_OFF  ((size_t)8404993)    // new_embed_avg[8192,512]  = 4194304

// Transient regions (stream-ordered lifetimes):
//   zp f16[8192*512] = floats [0, 2097152)       dead after dist; ZQ written by refine
//   cp f16[8192*512] = floats [2097152, 4194304) dead after dist; ends exactly at IDX_OFF
//   slab u64[8192][128] (t-major, {top1,top2} pairs per bn) = 8 MB inside NEA
//     region; written by dist, read by refine, dead before finalize writes NEA.
//     SLAB_F_OFF chosen 16-byte aligned (byte 33619984).
//   NCB region doubles as embed_sum accumulator: zeroed by prep, atomicAdd by
//     refine, consumed+overwritten by finalize.
#define CP_F_OFF   ((size_t)2097152)
#define SLAB_F_OFF ((size_t)8404996)

// d_ws layout (float offsets) — small scratch only (~100 KB)
#define WS_ZNORM  0
#define WS_ENORM  8192
#define WS_ICOUNT 16384   // int[8192]
#define WS_NSUM   24576   // accumulates sum(cluster_size)
#define WS_LOSS   24577

typedef _Float16 half8 __attribute__((ext_vector_type(8)));
typedef float floatx4 __attribute__((ext_vector_type(4)));
typedef unsigned long long ull;

__device__ __forceinline__ void gload16(const void* g, void* l) {
    __builtin_amdgcn_global_load_lds(
        (const __attribute__((address_space(1))) void*)g,
        (__attribute__((address_space(3))) void*)l, 16, 0, 0);
}

__device__ inline ull shfl_xor_u64(ull v, int m) {
    int lo = (int)(unsigned)(v & 0xFFFFFFFFull);
    int hi = (int)(unsigned)(v >> 32);
    lo = __shfl_xor(lo, m, 64);
    hi = __shfl_xor(hi, m, 64);
    return ((ull)(unsigned)hi << 32) | (unsigned)lo;
}
__device__ inline ull umin64(ull a, ull b) { return a < b ? a : b; }
__device__ inline ull umax64(ull a, ull b) { return a > b ? a : b; }

// ---- K1: f16 convert pack + row norms + zero accumulators -------------------
__global__ __launch_bounds__(256) void prep_kernel(const float* __restrict__ z,
                                                   const float* __restrict__ cb,
                                                   _Float16* __restrict__ zp,
                                                   _Float16* __restrict__ cp,
                                                   float* __restrict__ ws,
                                                   float* __restrict__ out,
                                                   int* __restrict__ icount) {
    int row = blockIdx.x;           // 0..16383
    int tid = threadIdx.x;

    // zero the embed_sum accumulator (NCB staging): exact cover 16384*256 dwords
    out[NCB_OFF + (size_t)row * 256 + tid] = 0.0f;
    // block 0 zeroes ws counters
    if (row == 0) {
        for (int j = tid; j < 8192; j += 256) icount[j] = 0;
        if (tid == 0) { ws[WS_NSUM] = 0.0f; ws[WS_LOSS] = 0.0f; }
    }

    const float* src;
    _Float16* dst;
    float* nrm;
    if (row < T_TOK) { src = z + (size_t)row * C_DIM; dst = zp + (size_t)row * C_DIM; nrm = ws + WS_ZNORM + row; }
    else { int r = row - T_TOK; src = cb + (size_t)r * C_DIM; dst = cp + (size_t)r * C_DIM; nrm = ws + WS_ENORM + r; }
    float a = src[tid], b = src[tid + 256];
    dst[tid] = (_Float16)a;
    dst[tid + 256] = (_Float16)b;
    float s = a * a + b * b;
    #pragma unroll
    for (int m = 32; m; m >>= 1) s += __shfl_down(s, m, 64);
    __shared__ float red[4];
    if ((tid & 63) == 0) red[tid >> 6] = s;
    __syncthreads();
    if (tid == 0) nrm[0] = (red[0] + red[1]) + (red[2] + red[3]);
}

// ---- K2: coarse f16 MFMA GEMM (K=512) + per-slice top-2 slab (t-major) ------
__global__ __launch_bounds__(256) void dist_mfma_kernel(
        const _Float16* __restrict__ zp, const _Float16* __restrict__ cp,
        const float* __restrict__ znorm, const float* __restrict__ enorm,
        ull* __restrict__ slab) {
    __shared__ __align__(16) _Float16 As[128 * 32];
    __shared__ __align__(16) _Float16 Bs[128 * 32];
    __shared__ ull red2[128][2][2];
    const int tid = threadIdx.x;
    const int w = tid >> 6, lane = tid & 63;
    const int quad = lane >> 4, lr = lane & 15;
    const int wm = w >> 1, wn = w & 1;

    const int GRID_N = 64, GROUP_M = 16;
    int pid = blockIdx.x;
    int per = GROUP_M * GRID_N;
    int g = pid / per;
    int local = pid % per;
    int bm = g * GROUP_M + (local & (GROUP_M - 1));
    int bn = local / GROUP_M;
    const int mBase = bm * 128, nBase = bn * 128;

    int r0 = (w * 2 + 0) * 16 + (lane >> 2);
    int r1 = (w * 2 + 1) * 16 + (lane >> 2);
    int cq = (((lane & 3) ^ ((lane >> 3) & 3))) * 8;
    const _Float16* ga0 = zp + (size_t)(mBase + r0) * C_DIM + cq;
    const _Float16* ga1 = zp + (size_t)(mBase + r1) * C_DIM + cq;
    const _Float16* gb0 = cp + (size_t)(nBase + r0) * C_DIM + cq;
    const _Float16* gb1 = cp + (size_t)(nBase + r1) * C_DIM + cq;
    _Float16* la0 = As + (w * 2 + 0) * 512;
    _Float16* la1 = As + (w * 2 + 1) * 512;
    _Float16* lb0 = Bs + (w * 2 + 0) * 512;
    _Float16* lb1 = Bs + (w * 2 + 1) * 512;

    const int slotA = (quad ^ ((lr >> 1) & 3)) * 8;
    const _Float16* aFrag = As + ((size_t)(wm * 64 + lr)) * 32 + slotA;
    const _Float16* bFrag = Bs + ((size_t)(wn * 64 + lr)) * 32 + slotA;

    floatx4 acc[4][4] = {};

    for (int it = 0; it < 16; ++it) {
        __syncthreads();
        gload16(ga0, la0);
        gload16(ga1, la1);
        gload16(gb0, lb0);
        gload16(gb1, lb1);
        ga0 += 32; ga1 += 32; gb0 += 32; gb1 += 32;
        __syncthreads();
        half8 af[4], bf[4];
        #pragma unroll
        for (int i = 0; i < 4; ++i) af[i] = *(const half8*)(aFrag + i * 16 * 32);
        #pragma unroll
        for (int j = 0; j < 4; ++j) bf[j] = *(const half8*)(bFrag + j * 16 * 32);
        #pragma unroll
        for (int i = 0; i < 4; ++i)
            #pragma unroll
            for (int j = 0; j < 4; ++j)
                acc[i][j] = __builtin_amdgcn_mfma_f32_16x16x32_f16(af[i], bf[j], acc[i][j], 0, 0, 0);
    }

    float en[4];
    #pragma unroll
    for (int j = 0; j < 4; ++j) en[j] = enorm[nBase + wn * 64 + j * 16 + lr];
    #pragma unroll
    for (int i = 0; i < 4; ++i) {
        #pragma unroll
        for (int r = 0; r < 4; ++r) {
            int lrow = wm * 64 + i * 16 + quad * 4 + r;
            float zn = znorm[mBase + lrow];
            ull t1 = ~0ull, t2 = ~0ull;
            #pragma unroll
            for (int j = 0; j < 4; ++j) {
                int n = nBase + wn * 64 + j * 16 + lr;
                float s = (zn - 2.0f * acc[i][j][r]) + en[j];
                ull p = ((ull)__float_as_uint(s) << 32) | (unsigned)n;
                if (p < t1) { t2 = t1; t1 = p; } else if (p < t2) t2 = p;
            }
            #pragma unroll
            for (int msk = 1; msk < 16; msk <<= 1) {
                ull o1 = shfl_xor_u64(t1, msk);
                ull o2 = shfl_xor_u64(t2, msk);
                ull n1 = umin64(t1, o1);
                ull n2 = umin64(umax64(t1, o1), umin64(t2, o2));
                t1 = n1; t2 = n2;
            }
            if (lr == 0) { red2[lrow][wn][0] = t1; red2[lrow][wn][1] = t2; }
        }
    }
    __syncthreads();
    if (tid < 128) {
        ull a1 = red2[tid][0][0], a2 = red2[tid][0][1];
        ull b1 = red2[tid][1][0], b2 = red2[tid][1][1];
        ull m1 = umin64(a1, b1);
        ull m2 = umin64(umax64(a1, b1), umin64(a2, b2));
        // t-major pair: slab[t*128 + bn*2] = {top1, top2}; 16B-aligned store.
        // Scattered across t but L2 write-back coalesces (slab = 8 MB < L2).
        ull* p = &slab[(((size_t)(mBase + tid)) << 7) + (size_t)bn * 2];
        p[0] = m1;
        p[1] = m2;
    }
}

// ---- K3: refine + gather + embed_sum scatter + cs partial sums --------------
__global__ __launch_bounds__(256) void refine_gather_kernel(
        const float* __restrict__ z, const float* __restrict__ cb,
        const float* __restrict__ znorm, const float* __restrict__ enorm,
        const ull* __restrict__ slab, const float* __restrict__ cs,
        float* __restrict__ out, int* __restrict__ icount,
        float* __restrict__ ws) {
    int t = blockIdx.x;
    int tid = threadIdx.x;
    int wv = tid >> 6, lane = tid & 63;
    __shared__ ull s1[64];
    __shared__ float s2d[64];
    __shared__ float thrS;
    __shared__ unsigned char fullF[64];
    __shared__ int singles[64];
    __shared__ int scnt;
    __shared__ ull wred[4];
    __shared__ ull sbestS;

    // coalesced slab read: 64 lanes x 16B = the whole 1 KB row for token t
    if (tid < 64) {
        ulonglong2 pr = *(const ulonglong2*)&slab[((size_t)t << 7) + (size_t)tid * 2];
        s1[tid] = pr.x;
        s2d[tid] = __uint_as_float((unsigned)(pr.y >> 32));
    }
    if (tid == 0) scnt = 0;
    const float* zr = z + (size_t)t * C_DIM + lane * 8;
    float4 z0 = *(const float4*)zr;
    float4 z1 = *(const float4*)(zr + 4);
    __syncthreads();
    if (tid < 64) {
        ull v = s1[tid];
        #pragma unroll
        for (int m = 32; m; m >>= 1) v = umin64(v, shfl_xor_u64(v, m));
        if (tid == 0) thrS = __uint_as_float((unsigned)(v >> 32)) + MARGIN;
    }
    __syncthreads();
    float thr = thrS;
    if (tid < 64) {
        float d1 = __uint_as_float((unsigned)(s1[tid] >> 32));
        bool full = s2d[tid] < thr;
        fullF[tid] = full ? 1 : 0;
        if (!full && d1 < thr) {
            int p = atomicAdd(&scnt, 1);
            singles[p] = (int)(unsigned)(s1[tid] & 0xFFFFFFFFull);
        }
    }
    __syncthreads();
    float zn = znorm[t];
    ull lbest = ~0ull;

    for (int bn = 0; bn < 64; ++bn) {
        if (!fullF[bn]) continue;
        int nb = bn * 128;
        for (int rep = 0; rep < 32; ++rep) {
            int n = nb + rep * 4 + wv;
            const float* cr = cb + (size_t)n * C_DIM + lane * 8;
            float4 c0 = *(const float4*)cr;
            float4 c1 = *(const float4*)(cr + 4);
            float p = 0.0f;
            p = fmaf(z0.x, c0.x, p); p = fmaf(z0.y, c0.y, p);
            p = fmaf(z0.z, c0.z, p); p = fmaf(z0.w, c0.w, p);
            p = fmaf(z1.x, c1.x, p); p = fmaf(z1.y, c1.y, p);
            p = fmaf(z1.z, c1.z, p); p = fmaf(z1.w, c1.w, p);
            #pragma unroll
            for (int m = 32; m; m >>= 1) p += __shfl_xor(p, m, 64);
            if (lane == 0) {
                float s = (zn - 2.0f * p) + enorm[n];
                ull pk = ((ull)__float_as_uint(s) << 32) | (unsigned)n;
                lbest = umin64(lbest, pk);
            }
        }
    }
    int sc = scnt;
    for (int base = 0; base < sc; base += 4) {
        int ci = base + wv;
        if (ci < sc) {
            int n = singles[ci];
            const float* cr = cb + (size_t)n * C_DIM + lane * 8;
            float4 c0 = *(const float4*)cr;
            float4 c1 = *(const float4*)(cr + 4);
            float p = 0.0f;
            p = fmaf(z0.x, c0.x, p); p = fmaf(z0.y, c0.y, p);
            p = fmaf(z0.z, c0.z, p); p = fmaf(z0.w, c0.w, p);
            p = fmaf(z1.x, c1.x, p); p = fmaf(z1.y, c1.y, p);
            p = fmaf(z1.z, c1.z, p); p = fmaf(z1.w, c1.w, p);
            #pragma unroll
            for (int m = 32; m; m >>= 1) p += __shfl_xor(p, m, 64);
            if (lane == 0) {
                float s = (zn - 2.0f * p) + enorm[n];
                ull pk = ((ull)__float_as_uint(s) << 32) | (unsigned)n;
                lbest = umin64(lbest, pk);
            }
        }
    }
    if (lane == 0) wred[wv] = lbest;
    __syncthreads();
    if (tid == 0)
        sbestS = umin64(umin64(wred[0], wred[1]), umin64(wred[2], wred[3]));
    __syncthreads();
    int idx = (int)(unsigned)(sbestS & 0xFFFFFFFFull);

    // fused gather (wave 0 holds the full z row: lane==tid for tid<64)
    if (tid < 64) {
        const float* qr = cb + (size_t)idx * C_DIM + tid * 8;
        float4 q0 = *(const float4*)qr;
        float4 q1 = *(const float4*)(qr + 4);
        float4 o0, o1;
        o0.x = z0.x + (q0.x - z0.x); o0.y = z0.y + (q0.y - z0.y);
        o0.z = z0.z + (q0.z - z0.z); o0.w = z0.w + (q0.w - z0.w);
        o1.x = z1.x + (q1.x - z1.x); o1.y = z1.y + (q1.y - z1.y);
        o1.z = z1.z + (q1.z - z1.z); o1.w = z1.w + (q1.w - z1.w);
        float* zq = out + ZQ_OFF + (size_t)t * C_DIM + tid * 8;
        *(float4*)zq = o0;
        *(float4*)(zq + 4) = o1;
        float d, l = 0.0f;
        d = z0.x - q0.x; l = fmaf(d, d, l);
        d = z0.y - q0.y; l = fmaf(d, d, l);
        d = z0.z - q0.z; l = fmaf(d, d, l);
        d = z0.w - q0.w; l = fmaf(d, d, l);
        d = z1.x - q1.x; l = fmaf(d, d, l);
        d = z1.y - q1.y; l = fmaf(d, d, l);
        d = z1.z - q1.z; l = fmaf(d, d, l);
        d = z1.w - q1.w; l = fmaf(d, d, l);
        #pragma unroll
        for (int m = 32; m; m >>= 1) l += __shfl_down(l, m, 64);
        if (tid == 0) {
            atomicAdd(&ws[WS_LOSS], l * (BETA / ((float)T_TOK * (float)C_DIM)));
            out[IDX_OFF + t] = (float)idx;
            atomicAdd(&icount[idx], 1);
        }
    }

    // embed_sum scatter into NCB staging: wave w adds elements {2w, 2w+1} of
    // each lane's 8-float slice (all waves hold the same z row slice).
    {
        float* es = out + NCB_OFF + (size_t)idx * C_DIM;
        float v0, v1;
        switch (wv) {
            case 0: v0 = z0.x; v1 = z0.y; break;
            case 1: v0 = z0.z; v1 = z0.w; break;
            case 2: v0 = z1.x; v1 = z1.y; break;
            default: v0 = z1.z; v1 = z1.w; break;
        }
        int c = lane * 8 + wv * 2;
        atomicAdd(&es[c], v0);
        atomicAdd(&es[c + 1], v1);
    }

    // 32 designated blocks reduce cluster_size -> ws[WS_NSUM] (sum(cs))
    if (t < 32) {
        float v = cs[t * 256 + tid];
        #pragma unroll
        for (int m = 32; m; m >>= 1) v += __shfl_down(v, m, 64);
        __shared__ float redcs[4];
        if ((tid & 63) == 0) redcs[tid >> 6] = v;
        __syncthreads();
        if (tid == 0)
            atomicAdd(&ws[WS_NSUM], (redcs[0] + redcs[1]) + (redcs[2] + redcs[3]));
    }
}

// ---- K4: finalize — NCS, new_embed_avg, new_codebook, loss copy -------------
__global__ __launch_bounds__(256) void finalize_kernel(const float* __restrict__ ea,
                                                       const float* __restrict__ cs,
                                                       const int* __restrict__ icount,
                                                       float* __restrict__ out,
                                                       const float* __restrict__ ws) {
    int k = blockIdx.x;
    int tid = threadIdx.x;
    // n = sum(new_cluster_size) = 0.99*sum(cs) + 0.01*T_TOK  (algebraic form;
    // output sensitivity to the summation-order delta is ~1e-8 relative)
    float sumcs = ws[WS_NSUM];
    float n = fmaxf(DECAY * sumcs + ONE_MINUS_DECAY * (float)T_TOK, 1.0f);
    float ncs = cs[k] * DECAY + (float)icount[k] * ONE_MINUS_DECAY;
    if (k == 0 && tid == 0) out[LOSS_OFF] = ws[WS_LOSS];
    if (tid == 0) out[NCS_OFF + k] = ncs;
    float smoothed = ((ncs + EPS_F) / (n + K_EPS)) * n;
    #pragma unroll
    for (int s = 0; s < 2; ++s) {
        int c = tid + s * 256;
        size_t o = (size_t)k * C_DIM + c;
        float es = out[NCB_OFF + o];                       // scattered embed_sum
        float nea = ea[o] * DECAY + es * ONE_MINUS_DECAY;
        out[NEA_OFF + o] = nea;
        out[NCB_OFF + o] = nea / smoothed;
    }
}

extern "C" void kernel_launch(void* const* d_in, const int* in_sizes, int n_in,
                              void* d_out, int out_size, void* d_ws, size_t ws_size,
                              hipStream_t stream) {
    const float* z  = (const float*)d_in[0];
    const float* cb = (const float*)d_in[1];
    const float* cs = (const float*)d_in[2];
    const float* ea = (const float*)d_in[3];
    float* out = (float*)d_out;
    float* ws  = (float*)d_ws;
    _Float16* zp = (_Float16*)out;
    _Float16* cp = (_Float16*)(out + CP_F_OFF);
    ull* slab = (ull*)(out + SLAB_F_OFF);
    int* icount = (int*)(ws + WS_ICOUNT);

    prep_kernel<<<16384, 256, 0, stream>>>(z, cb, zp, cp, ws, out, icount);
    dist_mfma_kernel<<<4096, 256, 0, stream>>>(zp, cp, ws + WS_ZNORM, ws + WS_ENORM, slab);
    refine_gather_kernel<<<8192, 256, 0, stream>>>(z, cb, ws + WS_ZNORM, ws + WS_ENORM,
                                                   slab, cs, out, icount, ws);
    finalize_kernel<<<8192, 256, 0, stream>>>(ea, cs, icount, out, ws);
}

// Round 6
// 395.797 us; speedup vs baseline: 1.0741x; 1.0741x over previous
//
#include <hip/hip_runtime.h>
#include <cstdint>
#include <cstddef>

// Problem constants
#define T_TOK 8192
#define K_CODE 8192
#define C_DIM 512
#define BETA 0.25f
#define DECAY 0.99f
#define ONE_MINUS_DECAY 0.01f
#define EPS_F 1e-5f
#define K_EPS 0.08192f
// Coarse-dist worst-case error bound: 2*||z||*||e||*2^-10 <= 0.025; margin = 2E + cushion
#define MARGIN 0.0625f

// d_out layout (floats, concatenated in reference return order)
#define ZQ_OFF   ((size_t)0)          // z_q_st      [8,1024,512] = 4194304
#define IDX_OFF  ((size_t)4194304)    // indices     [8,1024]     = 8192
#define LOSS_OFF ((size_t)4202496)    // vq_loss     scalar       = 1
#define NCB_OFF  ((size_t)4202497)    // new_codebook[8192,512]   = 4194304
#define NCS_OFF  ((size_t)8396801)    // new_cluster [8192]       = 8192
#define NEA_OFF  ((size_t)8404993)    // new_embed_avg[8192,512]  = 4194304

// Transient regions (stream-ordered lifetimes):
//   zp f16[8192*512] = floats [0, 2097152)       dead after dist; ZQ written by refine
//   cp f16[8192*512] = floats [2097152, 4194304) dead after dist; ends exactly at IDX_OFF
//   slab u64[8192][128] (t-major {top1,top2} pairs) = 8 MB inside NEA region;
//     written by dist, read by refine, dead before percode_final writes NEA.
#define CP_F_OFF   ((size_t)2097152)
#define SLAB_F_OFF ((size_t)8404996)   // byte 33619984, 16-aligned

// d_ws layout (float offsets) — small scratch only (~100 KB)
#define WS_ZNORM 0
#define WS_ENORM 8192
#define WS_IDX   16384   // int[8192] codebook index per token
#define WS_NSUM  24576   // sum(cluster_size), written by prep block 0
#define WS_LOSS  24577

typedef _Float16 half8 __attribute__((ext_vector_type(8)));
typedef float floatx4 __attribute__((ext_vector_type(4)));
typedef unsigned long long ull;

__device__ __forceinline__ void gload16(const void* g, void* l) {
    __builtin_amdgcn_global_load_lds(
        (const __attribute__((address_space(1))) void*)g,
        (__attribute__((address_space(3))) void*)l, 16, 0, 0);
}

__device__ inline ull shfl_xor_u64(ull v, int m) {
    int lo = (int)(unsigned)(v & 0xFFFFFFFFull);
    int hi = (int)(unsigned)(v >> 32);
    lo = __shfl_xor(lo, m, 64);
    hi = __shfl_xor(hi, m, 64);
    return ((ull)(unsigned)hi << 32) | (unsigned)lo;
}
__device__ inline ull umin64(ull a, ull b) { return a < b ? a : b; }
__device__ inline ull umax64(ull a, ull b) { return a > b ? a : b; }

// ---- K1: f16 convert pack + row norms; block 0 also computes sum(cs) --------
__global__ __launch_bounds__(256) void prep_kernel(const float* __restrict__ z,
                                                   const float* __restrict__ cb,
                                                   const float* __restrict__ cs,
                                                   _Float16* __restrict__ zp,
                                                   _Float16* __restrict__ cp,
                                                   float* __restrict__ ws) {
    int row = blockIdx.x;           // 0..16383
    int tid = threadIdx.x;

    const float* src;
    _Float16* dst;
    float* nrm;
    if (row < T_TOK) { src = z + (size_t)row * C_DIM; dst = zp + (size_t)row * C_DIM; nrm = ws + WS_ZNORM + row; }
    else { int r = row - T_TOK; src = cb + (size_t)r * C_DIM; dst = cp + (size_t)r * C_DIM; nrm = ws + WS_ENORM + r; }
    float a = src[tid], b = src[tid + 256];
    dst[tid] = (_Float16)a;
    dst[tid + 256] = (_Float16)b;
    float s = a * a + b * b;
    #pragma unroll
    for (int m = 32; m; m >>= 1) s += __shfl_down(s, m, 64);
    __shared__ float red[4];
    __shared__ float red2[4];
    if ((tid & 63) == 0) red[tid >> 6] = s;

    // block 0: single-block reduction of cluster_size -> ws[WS_NSUM]; zero loss
    if (row == 0) {
        float v = 0.0f;
        #pragma unroll
        for (int j = 0; j < 32; ++j) v += cs[j * 256 + tid];
        #pragma unroll
        for (int m = 32; m; m >>= 1) v += __shfl_down(v, m, 64);
        if ((tid & 63) == 0) red2[tid >> 6] = v;
    }
    __syncthreads();
    if (tid == 0) {
        nrm[0] = (red[0] + red[1]) + (red[2] + red[3]);
        if (row == 0) {
            ws[WS_NSUM] = (red2[0] + red2[1]) + (red2[2] + red2[3]);
            ws[WS_LOSS] = 0.0f;
        }
    }
}

// ---- K2: coarse f16 MFMA GEMM (K=512) + per-slice top-2 slab (t-major) ------
__global__ __launch_bounds__(256) void dist_mfma_kernel(
        const _Float16* __restrict__ zp, const _Float16* __restrict__ cp,
        const float* __restrict__ znorm, const float* __restrict__ enorm,
        ull* __restrict__ slab) {
    __shared__ __align__(16) _Float16 As[128 * 32];
    __shared__ __align__(16) _Float16 Bs[128 * 32];
    __shared__ ull red2[128][2][2];
    const int tid = threadIdx.x;
    const int w = tid >> 6, lane = tid & 63;
    const int quad = lane >> 4, lr = lane & 15;
    const int wm = w >> 1, wn = w & 1;

    const int GRID_N = 64, GROUP_M = 16;
    int pid = blockIdx.x;
    int per = GROUP_M * GRID_N;
    int g = pid / per;
    int local = pid % per;
    int bm = g * GROUP_M + (local & (GROUP_M - 1));
    int bn = local / GROUP_M;
    const int mBase = bm * 128, nBase = bn * 128;

    int r0 = (w * 2 + 0) * 16 + (lane >> 2);
    int r1 = (w * 2 + 1) * 16 + (lane >> 2);
    int cq = (((lane & 3) ^ ((lane >> 3) & 3))) * 8;
    const _Float16* ga0 = zp + (size_t)(mBase + r0) * C_DIM + cq;
    const _Float16* ga1 = zp + (size_t)(mBase + r1) * C_DIM + cq;
    const _Float16* gb0 = cp + (size_t)(nBase + r0) * C_DIM + cq;
    const _Float16* gb1 = cp + (size_t)(nBase + r1) * C_DIM + cq;
    _Float16* la0 = As + (w * 2 + 0) * 512;
    _Float16* la1 = As + (w * 2 + 1) * 512;
    _Float16* lb0 = Bs + (w * 2 + 0) * 512;
    _Float16* lb1 = Bs + (w * 2 + 1) * 512;

    const int slotA = (quad ^ ((lr >> 1) & 3)) * 8;
    const _Float16* aFrag = As + ((size_t)(wm * 64 + lr)) * 32 + slotA;
    const _Float16* bFrag = Bs + ((size_t)(wn * 64 + lr)) * 32 + slotA;

    floatx4 acc[4][4] = {};

    for (int it = 0; it < 16; ++it) {
        __syncthreads();
        gload16(ga0, la0);
        gload16(ga1, la1);
        gload16(gb0, lb0);
        gload16(gb1, lb1);
        ga0 += 32; ga1 += 32; gb0 += 32; gb1 += 32;
        __syncthreads();
        half8 af[4], bf[4];
        #pragma unroll
        for (int i = 0; i < 4; ++i) af[i] = *(const half8*)(aFrag + i * 16 * 32);
        #pragma unroll
        for (int j = 0; j < 4; ++j) bf[j] = *(const half8*)(bFrag + j * 16 * 32);
        #pragma unroll
        for (int i = 0; i < 4; ++i)
            #pragma unroll
            for (int j = 0; j < 4; ++j)
                acc[i][j] = __builtin_amdgcn_mfma_f32_16x16x32_f16(af[i], bf[j], acc[i][j], 0, 0, 0);
    }

    float en[4];
    #pragma unroll
    for (int j = 0; j < 4; ++j) en[j] = enorm[nBase + wn * 64 + j * 16 + lr];
    #pragma unroll
    for (int i = 0; i < 4; ++i) {
        #pragma unroll
        for (int r = 0; r < 4; ++r) {
            int lrow = wm * 64 + i * 16 + quad * 4 + r;
            float zn = znorm[mBase + lrow];
            ull t1 = ~0ull, t2 = ~0ull;
            #pragma unroll
            for (int j = 0; j < 4; ++j) {
                int n = nBase + wn * 64 + j * 16 + lr;
                float s = (zn - 2.0f * acc[i][j][r]) + en[j];
                ull p = ((ull)__float_as_uint(s) << 32) | (unsigned)n;
                if (p < t1) { t2 = t1; t1 = p; } else if (p < t2) t2 = p;
            }
            #pragma unroll
            for (int msk = 1; msk < 16; msk <<= 1) {
                ull o1 = shfl_xor_u64(t1, msk);
                ull o2 = shfl_xor_u64(t2, msk);
                ull n1 = umin64(t1, o1);
                ull n2 = umin64(umax64(t1, o1), umin64(t2, o2));
                t1 = n1; t2 = n2;
            }
            if (lr == 0) { red2[lrow][wn][0] = t1; red2[lrow][wn][1] = t2; }
        }
    }
    __syncthreads();
    if (tid < 128) {
        ull a1 = red2[tid][0][0], a2 = red2[tid][0][1];
        ull b1 = red2[tid][1][0], b2 = red2[tid][1][1];
        ull m1 = umin64(a1, b1);
        ull m2 = umin64(umax64(a1, b1), umin64(a2, b2));
        ull* p = &slab[(((size_t)(mBase + tid)) << 7) + (size_t)bn * 2];
        p[0] = m1;
        p[1] = m2;
    }
}

// ---- K3: refine + gather (argmin, z_q_st, loss, idx) ------------------------
__global__ __launch_bounds__(256) void refine_gather_kernel(
        const float* __restrict__ z, const float* __restrict__ cb,
        const float* __restrict__ znorm, const float* __restrict__ enorm,
        const ull* __restrict__ slab,
        float* __restrict__ out, int* __restrict__ widx,
        float* __restrict__ ws) {
    int t = blockIdx.x;
    int tid = threadIdx.x;
    int wv = tid >> 6, lane = tid & 63;
    __shared__ ull s1[64];
    __shared__ float s2d[64];
    __shared__ float thrS;
    __shared__ unsigned char fullF[64];
    __shared__ int singles[64];
    __shared__ int scnt;
    __shared__ ull wred[4];
    __shared__ ull sbestS;

    // coalesced slab read: 64 lanes x 16B = the whole 1 KB row for token t
    if (tid < 64) {
        ulonglong2 pr = *(const ulonglong2*)&slab[((size_t)t << 7) + (size_t)tid * 2];
        s1[tid] = pr.x;
        s2d[tid] = __uint_as_float((unsigned)(pr.y >> 32));
    }
    if (tid == 0) scnt = 0;
    const float* zr = z + (size_t)t * C_DIM + lane * 8;
    float4 z0 = *(const float4*)zr;
    float4 z1 = *(const float4*)(zr + 4);
    __syncthreads();
    if (tid < 64) {
        ull v = s1[tid];
        #pragma unroll
        for (int m = 32; m; m >>= 1) v = umin64(v, shfl_xor_u64(v, m));
        if (tid == 0) thrS = __uint_as_float((unsigned)(v >> 32)) + MARGIN;
    }
    __syncthreads();
    float thr = thrS;
    if (tid < 64) {
        float d1 = __uint_as_float((unsigned)(s1[tid] >> 32));
        bool full = s2d[tid] < thr;
        fullF[tid] = full ? 1 : 0;
        if (!full && d1 < thr) {
            int p = atomicAdd(&scnt, 1);
            singles[p] = (int)(unsigned)(s1[tid] & 0xFFFFFFFFull);
        }
    }
    __syncthreads();
    float zn = znorm[t];
    ull lbest = ~0ull;

    for (int bn = 0; bn < 64; ++bn) {
        if (!fullF[bn]) continue;
        int nb = bn * 128;
        for (int rep = 0; rep < 32; ++rep) {
            int n = nb + rep * 4 + wv;
            const float* cr = cb + (size_t)n * C_DIM + lane * 8;
            float4 c0 = *(const float4*)cr;
            float4 c1 = *(const float4*)(cr + 4);
            float p = 0.0f;
            p = fmaf(z0.x, c0.x, p); p = fmaf(z0.y, c0.y, p);
            p = fmaf(z0.z, c0.z, p); p = fmaf(z0.w, c0.w, p);
            p = fmaf(z1.x, c1.x, p); p = fmaf(z1.y, c1.y, p);
            p = fmaf(z1.z, c1.z, p); p = fmaf(z1.w, c1.w, p);
            #pragma unroll
            for (int m = 32; m; m >>= 1) p += __shfl_xor(p, m, 64);
            if (lane == 0) {
                float s = (zn - 2.0f * p) + enorm[n];
                ull pk = ((ull)__float_as_uint(s) << 32) | (unsigned)n;
                lbest = umin64(lbest, pk);
            }
        }
    }
    int sc = scnt;
    for (int base = 0; base < sc; base += 4) {
        int ci = base + wv;
        if (ci < sc) {
            int n = singles[ci];
            const float* cr = cb + (size_t)n * C_DIM + lane * 8;
            float4 c0 = *(const float4*)cr;
            float4 c1 = *(const float4*)(cr + 4);
            float p = 0.0f;
            p = fmaf(z0.x, c0.x, p); p = fmaf(z0.y, c0.y, p);
            p = fmaf(z0.z, c0.z, p); p = fmaf(z0.w, c0.w, p);
            p = fmaf(z1.x, c1.x, p); p = fmaf(z1.y, c1.y, p);
            p = fmaf(z1.z, c1.z, p); p = fmaf(z1.w, c1.w, p);
            #pragma unroll
            for (int m = 32; m; m >>= 1) p += __shfl_xor(p, m, 64);
            if (lane == 0) {
                float s = (zn - 2.0f * p) + enorm[n];
                ull pk = ((ull)__float_as_uint(s) << 32) | (unsigned)n;
                lbest = umin64(lbest, pk);
            }
        }
    }
    if (lane == 0) wred[wv] = lbest;
    __syncthreads();
    if (tid == 0)
        sbestS = umin64(umin64(wred[0], wred[1]), umin64(wred[2], wred[3]));
    __syncthreads();
    int idx = (int)(unsigned)(sbestS & 0xFFFFFFFFull);

    // fused gather (wave 0 holds the full z row: lane==tid for tid<64)
    if (tid < 64) {
        const float* qr = cb + (size_t)idx * C_DIM + tid * 8;
        float4 q0 = *(const float4*)qr;
        float4 q1 = *(const float4*)(qr + 4);
        float4 o0, o1;
        o0.x = z0.x + (q0.x - z0.x); o0.y = z0.y + (q0.y - z0.y);
        o0.z = z0.z + (q0.z - z0.z); o0.w = z0.w + (q0.w - z0.w);
        o1.x = z1.x + (q1.x - z1.x); o1.y = z1.y + (q1.y - z1.y);
        o1.z = z1.z + (q1.z - z1.z); o1.w = z1.w + (q1.w - z1.w);
        float* zq = out + ZQ_OFF + (size_t)t * C_DIM + tid * 8;
        *(float4*)zq = o0;
        *(float4*)(zq + 4) = o1;
        float d, l = 0.0f;
        d = z0.x - q0.x; l = fmaf(d, d, l);
        d = z0.y - q0.y; l = fmaf(d, d, l);
        d = z0.z - q0.z; l = fmaf(d, d, l);
        d = z0.w - q0.w; l = fmaf(d, d, l);
        d = z1.x - q1.x; l = fmaf(d, d, l);
        d = z1.y - q1.y; l = fmaf(d, d, l);
        d = z1.z - q1.z; l = fmaf(d, d, l);
        d = z1.w - q1.w; l = fmaf(d, d, l);
        #pragma unroll
        for (int m = 32; m; m >>= 1) l += __shfl_down(l, m, 64);
        if (tid == 0) {
            atomicAdd(&ws[WS_LOSS], l * (BETA / ((float)T_TOK * (float)C_DIM)));
            out[IDX_OFF + t] = (float)idx;
            widx[t] = idx;
        }
    }
}

// ---- K4: per-code segment-sum (scan cached idx array) + finalize ------------
// Block k scans all 8192 idx (32 KB, L2-resident broadcast), builds its match
// list in LDS (avg ~1 entry), sums those z rows coalesced, then writes
// ncs/nea/ncb directly. No atomics, no scan/scatter passes.
__global__ __launch_bounds__(256) void percode_final_kernel(
        const float* __restrict__ z, const float* __restrict__ cs,
        const float* __restrict__ ea, const int* __restrict__ widx,
        float* __restrict__ out, const float* __restrict__ ws) {
    int k = blockIdx.x;
    int tid = threadIdx.x;
    __shared__ unsigned short lst[8192];   // worst case: all tokens -> one code
    __shared__ int cnt;
    if (tid == 0) cnt = 0;
    __syncthreads();
    for (int j = tid; j < 8192; j += 256) {
        if (widx[j] == k) {
            int p = atomicAdd(&cnt, 1);    // LDS atomic, tiny
            lst[p] = (unsigned short)j;
        }
    }
    __syncthreads();
    int c = cnt;
    float a0 = 0.0f, a1 = 0.0f;
    for (int i = 0; i < c; ++i) {
        const float* zr = z + (size_t)lst[i] * C_DIM;
        a0 += zr[tid];
        a1 += zr[tid + 256];
    }
    // n = sum(new_cluster_size) = 0.99*sum(cs) + 0.01*T (algebraic; output
    // sensitivity to the summation-order delta is ~1e-8 relative)
    float n = fmaxf(DECAY * ws[WS_NSUM] + ONE_MINUS_DECAY * (float)T_TOK, 1.0f);
    float ncs = cs[k] * DECAY + (float)c * ONE_MINUS_DECAY;
    if (tid == 0) out[NCS_OFF + k] = ncs;
    if (k == 0 && tid == 0) out[LOSS_OFF] = ws[WS_LOSS];
    float smoothed = ((ncs + EPS_F) / (n + K_EPS)) * n;
    size_t o = (size_t)k * C_DIM + tid;
    float nea0 = ea[o] * DECAY + a0 * ONE_MINUS_DECAY;
    float nea1 = ea[o + 256] * DECAY + a1 * ONE_MINUS_DECAY;
    out[NEA_OFF + o] = nea0;
    out[NEA_OFF + o + 256] = nea1;
    out[NCB_OFF + o] = nea0 / smoothed;
    out[NCB_OFF + o + 256] = nea1 / smoothed;
}

extern "C" void kernel_launch(void* const* d_in, const int* in_sizes, int n_in,
                              void* d_out, int out_size, void* d_ws, size_t ws_size,
                              hipStream_t stream) {
    const float* z  = (const float*)d_in[0];
    const float* cb = (const float*)d_in[1];
    const float* cs = (const float*)d_in[2];
    const float* ea = (const float*)d_in[3];
    float* out = (float*)d_out;
    float* ws  = (float*)d_ws;
    _Float16* zp = (_Float16*)out;
    _Float16* cp = (_Float16*)(out + CP_F_OFF);
    ull* slab = (ull*)(out + SLAB_F_OFF);
    int* widx = (int*)(ws + WS_IDX);

    prep_kernel<<<16384, 256, 0, stream>>>(z, cb, cs, zp, cp, ws);
    dist_mfma_kernel<<<4096, 256, 0, stream>>>(zp, cp, ws + WS_ZNORM, ws + WS_ENORM, slab);
    refine_gather_kernel<<<8192, 256, 0, stream>>>(z, cb, ws + WS_ZNORM, ws + WS_ENORM,
                                                   slab, out, widx, ws);
    percode_final_kernel<<<8192, 256, 0, stream>>>(z, cs, ea, widx, out, ws);
}